// Round 3
// baseline (2999.001 us; speedup 1.0000x reference)
//
#include <hip/hip_runtime.h>
#include <math.h>

// ---- problem constants (match reference) ----
static constexpr int NYI  = 256;           // interior
static constexpr int PMLW = 20;            // pml width
static constexpr int NY   = NYI + 2*PMLW;  // 296
static constexpr int NX   = NYI + 2*PMLW;  // 296
static constexpr int NCELL = NY * NX;      // 87616
static constexpr int NS   = 2;             // shots
static constexpr int NSRC = 8;
static constexpr int NREC = 64;
static constexpr int NT   = 64;
static constexpr float DXF = 4.0f;
static constexpr float DTF = 5e-4f;
static constexpr float FC1 = 9.0f / 8.0f;
static constexpr float FC2 = -1.0f / 24.0f;
static constexpr float INV_DX = 1.0f / DXF;

// wave fields needing stencil access (global); CPML memory fields live in registers
enum { F_VY=0, F_VX, F_SYY, F_SXY, F_SXX, NWF };
static constexpr int SIG_OFF = NWF * NS * NCELL;   // max-vel scalar (atomicMax target)
static constexpr int CNT_OFF = SIG_OFF + 32;       // barrier arrival counter (own cacheline)
static constexpr int GEN_OFF = SIG_OFF + 64;       // barrier generation     (own cacheline)

static constexpr int NB = (NCELL + 255) / 256;     // 343 blocks, 1 thread/cell (both shots)

__device__ __forceinline__ float ldz(const float* __restrict__ f, int y, int x) {
    return (y >= 0 && y < NY && x >= 0 && x < NX) ? f[y * NX + x] : 0.0f;
}

// grid-wide barrier: plain launch, device-scope atomics + agent fences.
// Safe iff all NB blocks co-resident (guaranteed: launch_bounds(256,2) -> >=2 blk/CU -> 512 slots).
__device__ __forceinline__ void gsync(int* cnt, int* gen) {
    __syncthreads();
    if (threadIdx.x == 0) {
        __builtin_amdgcn_fence(__ATOMIC_RELEASE, "agent");   // flush my data stores
        int g = __hip_atomic_load(gen, __ATOMIC_RELAXED, __HIP_MEMORY_SCOPE_AGENT);
        int arrived = __hip_atomic_fetch_add(cnt, 1, __ATOMIC_ACQ_REL, __HIP_MEMORY_SCOPE_AGENT);
        if (arrived == NB - 1) {
            __hip_atomic_store(cnt, 0, __ATOMIC_RELAXED, __HIP_MEMORY_SCOPE_AGENT);
            __hip_atomic_store(gen, g + 1, __ATOMIC_RELEASE, __HIP_MEMORY_SCOPE_AGENT);
        } else {
            while (__hip_atomic_load(gen, __ATOMIC_RELAXED, __HIP_MEMORY_SCOPE_AGENT) == g)
                __builtin_amdgcn_s_sleep(2);
        }
        __builtin_amdgcn_fence(__ATOMIC_ACQUIRE, "agent");   // invalidate L1/L2 before data reads
    }
    __syncthreads();
}

__global__ __launch_bounds__(256, 2)
void elastic_all(const float* __restrict__ lamb, const float* __restrict__ mu,
                 const float* __restrict__ buoy, const float* __restrict__ amps,
                 const int* __restrict__ src_loc, const int* __restrict__ rec_loc,
                 float* __restrict__ out, float* __restrict__ ws)
{
    int* bcnt = (int*)(ws + CNT_OFF);
    int* bgen = (int*)(ws + GEN_OFF);
    const int tid  = blockIdx.x * blockDim.x + threadIdx.x;
    const int cell = tid;
    const bool active = cell < NCELL;

    int y = 0, x = 0;
    float buo = 0.f, l2m = 0.f, lam = 0.f, muv = 0.f;
    float v = 0.f;
    if (active) {
        y = cell / NX; x = cell - y * NX;
        int iy = min(max(y - PMLW, 0), NYI - 1);
        int ix = min(max(x - PMLW, 0), NYI - 1);
        lam = lamb[iy * NYI + ix];
        muv = mu  [iy * NYI + ix];
        buo = buoy[iy * NYI + ix];
        l2m = lam + 2.0f * muv;
        v = sqrtf(l2m * buo);
        // zero-init the 10 global wave fields for this cell
        #pragma unroll
        for (int f = 0; f < NWF * NS; ++f)
            ws[f * NCELL + cell] = 0.0f;
    }
    // grid max of wave speed: wave-64 reduce + one atomic per wave (values >= 0)
    #pragma unroll
    for (int off = 32; off > 0; off >>= 1)
        v = fmaxf(v, __shfl_down(v, off));
    if ((threadIdx.x & 63) == 0)
        atomicMax((int*)(ws + SIG_OFF), __float_as_int(v));

    // source hit-mask for this cell (bit i = (shot,src) flat index i)
    int smask = 0;
    #pragma unroll
    for (int i = 0; i < NS * NSRC; ++i) {
        int sy = src_loc[2 * i + 0] + PMLW;
        int sx = src_loc[2 * i + 1] + PMLW;
        if (active && sy == y && sx == x) smask |= (1 << i);
    }

    gsync(bcnt, bgen);   // zeros + max-vel visible

    // CPML damping coefficients for this cell (row/col profiles, NY==NX)
    const float max_vel = ws[SIG_OFF];
    const float sig_max = 3.0f * max_vel * logf(1000.0f) / (2.0f * PMLW * DXF);
    auto prof = [&](int i) {
        float fi = (float)i;
        float d1 = fmaxf((float)PMLW - fi, 0.0f);
        float d2 = fmaxf(fi - (float)(NY - 1 - PMLW), 0.0f);
        float dd = fmaxf(d1, d2) * (1.0f / (float)PMLW);
        return expf(-(sig_max * dd * dd) * DTF);
    };
    const float by = prof(y), ay = by - 1.0f;
    const float bx = prof(x), ax = bx - 1.0f;

    // register state: own wave values + all 8 CPML memory fields, per shot
    float rvy[NS]   = {0.f, 0.f}, rvx[NS]   = {0.f, 0.f};
    float rsyy[NS]  = {0.f, 0.f}, rsxy[NS]  = {0.f, 0.f}, rsxx[NS] = {0.f, 0.f};
    float msyyy[NS] = {0.f, 0.f}, msxyy[NS] = {0.f, 0.f};
    float msxyx[NS] = {0.f, 0.f}, msxxx[NS] = {0.f, 0.f};
    float mvyy[NS]  = {0.f, 0.f}, mvyx[NS]  = {0.f, 0.f};
    float mvxy[NS]  = {0.f, 0.f}, mvxx[NS]  = {0.f, 0.f};

    for (int t = 0; t < NT; ++t) {
        // ---------------- velocity half-step ----------------
        if (active) {
            #pragma unroll
            for (int s = 0; s < NS; ++s) {
                const float* syy = ws + (F_SYY * NS + s) * NCELL;
                const float* sxy = ws + (F_SXY * NS + s) * NCELL;
                const float* sxx = ws + (F_SXX * NS + s) * NCELL;
                float d, mm;
                d = (FC1 * (ldz(syy,y,x) - ldz(syy,y-1,x)) + FC2 * (ldz(syy,y+1,x) - ldz(syy,y-2,x))) * INV_DX;
                mm = by * msyyy[s] + ay * d;  msyyy[s] = mm;  float dsyy_y = d + mm;
                d = (FC1 * (ldz(sxy,y,x) - ldz(sxy,y,x-1)) + FC2 * (ldz(sxy,y,x+1) - ldz(sxy,y,x-2))) * INV_DX;
                mm = bx * msxyx[s] + ax * d;  msxyx[s] = mm;  float dsxy_x = d + mm;
                rvy[s] += DTF * buo * (dsyy_y + dsxy_x);
                d = (FC1 * (ldz(sxy,y,x) - ldz(sxy,y-1,x)) + FC2 * (ldz(sxy,y+1,x) - ldz(sxy,y-2,x))) * INV_DX;
                mm = by * msxyy[s] + ay * d;  msxyy[s] = mm;  float dsxy_y = d + mm;
                d = (FC1 * (ldz(sxx,y,x) - ldz(sxx,y,x-1)) + FC2 * (ldz(sxx,y,x+1) - ldz(sxx,y,x-2))) * INV_DX;
                mm = bx * msxxx[s] + ax * d;  msxxx[s] = mm;  float dsxx_x = d + mm;
                rvx[s] += DTF * buo * (dsxy_y + dsxx_x);
            }
            // source injection (src_b == this cell's buoyancy; duplicates accumulate)
            if (smask) {
                #pragma unroll
                for (int i = 0; i < NS * NSRC; ++i) {
                    if (smask & (1 << i))
                        rvy[i / NSRC] += DTF * buo * amps[i * NT + t];
                }
            }
            #pragma unroll
            for (int s = 0; s < NS; ++s) {
                ws[(F_VY * NS + s) * NCELL + cell] = rvy[s];
                ws[(F_VX * NS + s) * NCELL + cell] = rvx[s];
            }
        }
        gsync(bcnt, bgen);   // velocities visible

        // receivers read vy (one thread per (shot,rec) entry)
        if (tid < NS * NREC) {
            int ry = rec_loc[2 * tid + 0] + PMLW;
            int rx = rec_loc[2 * tid + 1] + PMLW;
            int shot = tid / NREC;
            out[tid * NT + t] = ws[(F_VY * NS + shot) * NCELL + ry * NX + rx];
        }

        // ---------------- stress half-step ----------------
        if (active) {
            #pragma unroll
            for (int s = 0; s < NS; ++s) {
                const float* vyg = ws + (F_VY * NS + s) * NCELL;
                const float* vxg = ws + (F_VX * NS + s) * NCELL;
                float d, mm;
                d = (FC1 * (ldz(vyg,y+1,x) - ldz(vyg,y,x)) + FC2 * (ldz(vyg,y+2,x) - ldz(vyg,y-1,x))) * INV_DX;
                mm = by * mvyy[s] + ay * d;  mvyy[s] = mm;  float dvy_y = d + mm;
                d = (FC1 * (ldz(vxg,y,x+1) - ldz(vxg,y,x)) + FC2 * (ldz(vxg,y,x+2) - ldz(vxg,y,x-1))) * INV_DX;
                mm = bx * mvxx[s] + ax * d;  mvxx[s] = mm;  float dvx_x = d + mm;
                rsyy[s] += DTF * (l2m * dvy_y + lam * dvx_x);
                rsxx[s] += DTF * (lam * dvy_y + l2m * dvx_x);
                d = (FC1 * (ldz(vyg,y,x+1) - ldz(vyg,y,x)) + FC2 * (ldz(vyg,y,x+2) - ldz(vyg,y,x-1))) * INV_DX;
                mm = bx * mvyx[s] + ax * d;  mvyx[s] = mm;  float dvy_x = d + mm;
                d = (FC1 * (ldz(vxg,y+1,x) - ldz(vxg,y,x)) + FC2 * (ldz(vxg,y+2,x) - ldz(vxg,y-1,x))) * INV_DX;
                mm = by * mvxy[s] + ay * d;  mvxy[s] = mm;  float dvx_y = d + mm;
                rsxy[s] += DTF * muv * (dvy_x + dvx_y);
                ws[(F_SYY * NS + s) * NCELL + cell] = rsyy[s];
                ws[(F_SXY * NS + s) * NCELL + cell] = rsxy[s];
                ws[(F_SXX * NS + s) * NCELL + cell] = rsxx[s];
            }
        }
        gsync(bcnt, bgen);   // stresses visible for next velocity half-step
    }
}

extern "C" void kernel_launch(void* const* d_in, const int* in_sizes, int n_in,
                              void* d_out, int out_size, void* d_ws, size_t ws_size,
                              hipStream_t stream) {
    const float* lamb    = (const float*)d_in[0];
    const float* mu      = (const float*)d_in[1];
    const float* buoy    = (const float*)d_in[2];
    const float* amps    = (const float*)d_in[3];
    const int*   src_loc = (const int*)d_in[4];
    const int*   rec_loc = (const int*)d_in[5];
    float* ws  = (float*)d_ws;
    float* out = (float*)d_out;

    // zero max-vel scalar + barrier counter/generation (ws is poisoned 0xAA each call)
    hipMemsetAsync(ws + SIG_OFF, 0, 96 * sizeof(float), stream);

    elastic_all<<<NB, 256, 0, stream>>>(lamb, mu, buoy, amps, src_loc, rec_loc, out, ws);
}

// Round 4
// 1049.135 us; speedup vs baseline: 2.8585x; 2.8585x over previous
//
#include <hip/hip_runtime.h>
#include <math.h>

// ---- problem constants (match reference) ----
static constexpr int NYI  = 256;
static constexpr int PMLW = 20;
static constexpr int NY   = 296, NX = 296;
static constexpr int NCELL = NY * NX;
static constexpr int NS   = 2;
static constexpr int NSRC = 8;
static constexpr int NREC = 64;
static constexpr int NT   = 64;
static constexpr float DXF = 4.0f;
static constexpr float DTF = 5e-4f;
static constexpr float FC1 = 9.0f / 8.0f;
static constexpr float FC2 = -1.0f / 24.0f;
static constexpr float INV_DX = 1.0f / DXF;

// ---- decomposition: 8x8 tiles of 37x37, one shot per block ----
static constexpr int TB = 8, TS = 37;          // 8*37 = 296 exactly
static constexpr int VS = TS + 4;              // 41: vel region (tile+2 halo, redundant)
static constexpr int SS = TS + 8;              // 45: stress region (tile+4 halo)
static constexpr int NBLK = TB * TB * NS;      // 128
static constexpr int NTHR = 512;
static constexpr int VAREA = VS * VS;          // 1681
static constexpr int TAREA = TS * TS;          // 1369
static constexpr int SFRAME = SS * SS - TAREA; // 656 frame cells
static constexpr int KV = 4, KT = 3;           // per-thread slots (512*4>=1681, 512*3>=1369)

// ---- global ws layout (floats): only stress fields + barrier words ----
static constexpr int GS_OFF  = 0;                    // stress [3][NS][NCELL]
static constexpr int SIG_OFF = 3 * NS * NCELL;
static constexpr int CNT_OFF = SIG_OFF + 32;
static constexpr int GEN_OFF = SIG_OFF + 64;

// grid barrier (validated in round 3): all NBLK blocks co-resident.
__device__ __forceinline__ void gsync(int* cnt, int* gen) {
    __syncthreads();                       // compiler emits vmcnt(0) drain per wave
    if (threadIdx.x == 0) {
        __builtin_amdgcn_fence(__ATOMIC_RELEASE, "agent");   // wb dirty L2 (only our strips)
        int g = __hip_atomic_load(gen, __ATOMIC_RELAXED, __HIP_MEMORY_SCOPE_AGENT);
        int arrived = __hip_atomic_fetch_add(cnt, 1, __ATOMIC_ACQ_REL, __HIP_MEMORY_SCOPE_AGENT);
        if (arrived == NBLK - 1) {
            __hip_atomic_store(cnt, 0, __ATOMIC_RELAXED, __HIP_MEMORY_SCOPE_AGENT);
            __hip_atomic_store(gen, g + 1, __ATOMIC_RELEASE, __HIP_MEMORY_SCOPE_AGENT);
        } else {
            while (__hip_atomic_load(gen, __ATOMIC_RELAXED, __HIP_MEMORY_SCOPE_AGENT) == g)
                __builtin_amdgcn_s_sleep(2);
        }
        __builtin_amdgcn_fence(__ATOMIC_ACQUIRE, "agent");   // inv L1/L2 (state is in LDS: cheap)
    }
    __syncthreads();
}

__global__ __launch_bounds__(NTHR, 1)
void elastic_fused(const float* __restrict__ lamb, const float* __restrict__ mu,
                   const float* __restrict__ buoy, const float* __restrict__ amps,
                   const int* __restrict__ src_loc, const int* __restrict__ rec_loc,
                   float* __restrict__ out, float* __restrict__ ws)
{
    __shared__ float sS[3][SS * SS];     // syy,sxy,sxx  (center computed, frame from neighbors)
    __shared__ float sV[2][VS * VS];     // vy,vx        (all computed locally, halo redundant)
    __shared__ float byt[VS], ayt[VS], bxt[VS], axt[VS];
    __shared__ float sAmp[NSRC * NT];
    __shared__ int   rcnt;
    __shared__ short rl_r[NREC];
    __shared__ int   rl_pos[NREC];

    int* bcnt = (int*)(ws + CNT_OFF);
    int* bgen = (int*)(ws + GEN_OFF);
    float* gstr = ws + GS_OFF;

    const int tid  = threadIdx.x;
    const int shot = blockIdx.x & 1;
    const int tb   = blockIdx.x >> 1;
    const int bty  = tb >> 3, btx = tb & 7;
    const int gy0  = bty * TS, gx0 = btx * TS;

    // ---- init: zero global stress slice (frames must read 0 at t=0) ----
    for (int i = blockIdx.x * NTHR + tid; i < 3 * NS * NCELL; i += NBLK * NTHR)
        ws[GS_OFF + i] = 0.0f;
    // zero LDS fields
    for (int i = tid; i < 3 * SS * SS; i += NTHR) ((float*)sS)[i] = 0.0f;
    for (int i = tid; i < 2 * VS * VS; i += NTHR) ((float*)sV)[i] = 0.0f;
    if (tid == 0) rcnt = 0;

    // ---- per-thread V-region slots (vel + its CPML memories, redundant halo-2) ----
    int   sidx_v[KV], vyv[KV], vxv[KV], smk[KV];
    float buo_v[KV];
    float msyyy[KV] = {0,0,0,0}, msxyx[KV] = {0,0,0,0};
    float msxyy[KV] = {0,0,0,0}, msxxx[KV] = {0,0,0,0};
    unsigned cvm = 0;
    #pragma unroll
    for (int k = 0; k < KV; ++k) {
        int vi = tid + NTHR * k;
        bool val = vi < VAREA;
        int vy_ = val ? vi / VS : 0;
        int vx_ = val ? vi - vy_ * VS : 0;
        int gy = gy0 - 2 + vy_, gx = gx0 - 2 + vx_;
        bool ing = val && gy >= 0 && gy < NY && gx >= 0 && gx < NX;
        if (ing) cvm |= 1u << k;
        vyv[k] = vy_; vxv[k] = vx_;
        sidx_v[k] = (vy_ + 2) * SS + (vx_ + 2);
        float b = 0.0f;
        if (ing) {
            int iy = min(max(gy - PMLW, 0), NYI - 1);
            int ix = min(max(gx - PMLW, 0), NYI - 1);
            b = buoy[iy * NYI + ix];
        }
        buo_v[k] = b;
        int sm = 0;
        #pragma unroll
        for (int s = 0; s < NSRC; ++s) {
            int sy = src_loc[(shot * NSRC + s) * 2 + 0] + PMLW;
            int sx = src_loc[(shot * NSRC + s) * 2 + 1] + PMLW;
            if (ing && sy == gy && sx == gx) sm |= 1 << s;
        }
        smk[k] = sm;
    }

    // ---- per-thread tile slots (stress + its CPML memories, owned) ----
    int   sidx_t[KT], vidx_t[KT], gidx_t[KT], tyt[KT], txt[KT];
    float lam_t[KT], mu_t[KT], l2m_t[KT];
    float mvyy[KT] = {0,0,0}, mvxx[KT] = {0,0,0}, mvyx[KT] = {0,0,0}, mvxy[KT] = {0,0,0};
    unsigned ctm = 0, ringm = 0;
    float vmax = 0.0f;
    #pragma unroll
    for (int k = 0; k < KT; ++k) {
        int ti = tid + NTHR * k;
        bool val = ti < TAREA;
        int ty = val ? ti / TS : 0;
        int tx = val ? ti - ty * TS : 0;
        int gy = gy0 + ty, gx = gx0 + tx;
        if (val) ctm |= 1u << k;
        if (val && (ty < 4 || ty >= TS - 4 || tx < 4 || tx >= TS - 4)) ringm |= 1u << k;
        tyt[k] = ty; txt[k] = tx;
        sidx_t[k] = (ty + 4) * SS + (tx + 4);
        vidx_t[k] = (ty + 2) * VS + (tx + 2);
        gidx_t[k] = gy * NX + gx;
        float la = 0.0f, m = 0.0f;
        if (val) {
            int iy = min(max(gy - PMLW, 0), NYI - 1);
            int ix = min(max(gx - PMLW, 0), NYI - 1);
            la = lamb[iy * NYI + ix];
            m  = mu  [iy * NYI + ix];
            float b = buoy[iy * NYI + ix];
            vmax = fmaxf(vmax, sqrtf((la + 2.0f * m) * b));
        }
        lam_t[k] = la; mu_t[k] = m; l2m_t[k] = la + 2.0f * m;
    }
    // grid max wave speed
    #pragma unroll
    for (int off = 32; off > 0; off >>= 1)
        vmax = fmaxf(vmax, __shfl_down(vmax, off));
    if ((tid & 63) == 0)
        atomicMax((int*)(ws + SIG_OFF), __float_as_int(vmax));

    __syncthreads();   // rcnt=0 + LDS zeros visible in-block
    // receivers of my shot inside my tile (unique owner)
    if (tid < NREC) {
        int r = tid;
        int ry = rec_loc[(shot * NREC + r) * 2 + 0] + PMLW;
        int rx = rec_loc[(shot * NREC + r) * 2 + 1] + PMLW;
        if (ry >= gy0 && ry < gy0 + TS && rx >= gx0 && rx < gx0 + TS) {
            int p = atomicAdd(&rcnt, 1);
            rl_r[p]   = (short)r;
            rl_pos[p] = (ry - gy0 + 2) * VS + (rx - gx0 + 2);
        }
    }
    // my shot's amplitudes -> LDS (avoid post-fence global reads in the loop)
    for (int i = tid; i < NSRC * NT; i += NTHR)
        sAmp[i] = amps[shot * NSRC * NT + i];

    gsync(bcnt, bgen);   // global zeros + vmax visible everywhere

    // CPML profile tables over local rows/cols
    const float max_vel = ws[SIG_OFF];
    const float sig_max = 3.0f * max_vel * logf(1000.0f) / (2.0f * PMLW * DXF);
    if (tid < VS) {
        auto prof = [&](int g) -> float {
            float fi = (float)g;
            float d1 = fmaxf((float)PMLW - fi, 0.0f);
            float d2 = fmaxf(fi - (float)(NY - 1 - PMLW), 0.0f);
            float dd = fmaxf(d1, d2) * (1.0f / (float)PMLW);
            return expf(-(sig_max * dd * dd) * DTF);
        };
        float b = prof(gy0 - 2 + tid); byt[tid] = b; ayt[tid] = b - 1.0f;
        b = prof(gx0 - 2 + tid);       bxt[tid] = b; axt[tid] = b - 1.0f;
    }
    __syncthreads();

    // ================= time loop: ONE grid barrier per step =================
    for (int t = 0; t < NT; ++t) {
        // P1: load stress frame (neighbor strips) from global into sS frame
        #pragma unroll
        for (int k = 0; k < 2; ++k) {
            int ff = tid + NTHR * k;
            if (ff < SFRAME) {
                int fy, fx;
                if (ff < 4 * SS)      { fy = ff / SS;                 fx = ff - fy * SS; }
                else if (ff < 8 * SS) { int r = ff - 4 * SS; fy = SS - 4 + r / SS; fx = r % SS; }
                else {
                    int r = ff - 8 * SS;
                    if (r < (SS - 8) * 4) { fy = 4 + (r >> 2); fx = r & 3; }
                    else { r -= (SS - 8) * 4; fy = 4 + (r >> 2); fx = SS - 4 + (r & 3); }
                }
                int gy = gy0 - 4 + fy, gx = gx0 - 4 + fx;
                bool in = gy >= 0 && gy < NY && gx >= 0 && gx < NX;
                int gi = gy * NX + gx;
                #pragma unroll
                for (int f = 0; f < 3; ++f)
                    sS[f][fy * SS + fx] = in ? gstr[(f * NS + shot) * NCELL + gi] : 0.0f;
            }
        }
        __syncthreads();

        // P2: velocity on V (tile + redundant 2-halo)
        #pragma unroll
        for (int k = 0; k < KV; ++k) {
            if (!((cvm >> k) & 1)) continue;
            int si = sidx_v[k];
            float by_ = byt[vyv[k]], ay_ = ayt[vyv[k]];
            float bx_ = bxt[vxv[k]], ax_ = axt[vxv[k]];
            float d, mm;
            d = (FC1 * (sS[0][si] - sS[0][si - SS]) + FC2 * (sS[0][si + SS] - sS[0][si - 2 * SS])) * INV_DX;
            mm = by_ * msyyy[k] + ay_ * d;  msyyy[k] = mm;  float dsyy_y = d + mm;
            d = (FC1 * (sS[1][si] - sS[1][si - 1]) + FC2 * (sS[1][si + 1] - sS[1][si - 2])) * INV_DX;
            mm = bx_ * msxyx[k] + ax_ * d;  msxyx[k] = mm;  float dsxy_x = d + mm;
            d = (FC1 * (sS[1][si] - sS[1][si - SS]) + FC2 * (sS[1][si + SS] - sS[1][si - 2 * SS])) * INV_DX;
            mm = by_ * msxyy[k] + ay_ * d;  msxyy[k] = mm;  float dsxy_y = d + mm;
            d = (FC1 * (sS[2][si] - sS[2][si - 1]) + FC2 * (sS[2][si + 1] - sS[2][si - 2])) * INV_DX;
            mm = bx_ * msxxx[k] + ax_ * d;  msxxx[k] = mm;  float dsxx_x = d + mm;
            int vi = tid + NTHR * k;   // sV flat index == V row-major index
            float nvy = sV[0][vi] + DTF * buo_v[k] * (dsyy_y + dsxy_x);
            float nvx = sV[1][vi] + DTF * buo_v[k] * (dsxy_y + dsxx_x);
            if (smk[k]) {
                #pragma unroll
                for (int s = 0; s < NSRC; ++s)
                    if ((smk[k] >> s) & 1) nvy += DTF * buo_v[k] * sAmp[s * NT + t];
            }
            sV[0][vi] = nvy;
            sV[1][vi] = nvx;
        }
        __syncthreads();

        // receivers: vy after injection (LDS-resident)
        if (tid < rcnt)
            out[(shot * NREC + rl_r[tid]) * NT + t] = sV[0][rl_pos[tid]];

        // P3: stress on tile (reads only sV; writes own sS center cell)
        #pragma unroll
        for (int k = 0; k < KT; ++k) {
            if (!((ctm >> k) & 1)) continue;
            int si = sidx_t[k], vi = vidx_t[k];
            float by_ = byt[tyt[k] + 2], ay_ = ayt[tyt[k] + 2];
            float bx_ = bxt[txt[k] + 2], ax_ = axt[txt[k] + 2];
            float d, mm;
            d = (FC1 * (sV[0][vi + VS] - sV[0][vi]) + FC2 * (sV[0][vi + 2 * VS] - sV[0][vi - VS])) * INV_DX;
            mm = by_ * mvyy[k] + ay_ * d;  mvyy[k] = mm;  float dvy_y = d + mm;
            d = (FC1 * (sV[1][vi + 1] - sV[1][vi]) + FC2 * (sV[1][vi + 2] - sV[1][vi - 1])) * INV_DX;
            mm = bx_ * mvxx[k] + ax_ * d;  mvxx[k] = mm;  float dvx_x = d + mm;
            sS[0][si] += DTF * (l2m_t[k] * dvy_y + lam_t[k] * dvx_x);
            sS[2][si] += DTF * (lam_t[k] * dvy_y + l2m_t[k] * dvx_x);
            d = (FC1 * (sV[0][vi + 1] - sV[0][vi]) + FC2 * (sV[0][vi + 2] - sV[0][vi - 1])) * INV_DX;
            mm = bx_ * mvyx[k] + ax_ * d;  mvyx[k] = mm;  float dvy_x = d + mm;
            d = (FC1 * (sV[1][vi + VS] - sV[1][vi]) + FC2 * (sV[1][vi + 2 * VS] - sV[1][vi - VS])) * INV_DX;
            mm = by_ * mvxy[k] + ay_ * d;  mvxy[k] = mm;  float dvx_y = d + mm;
            sS[1][si] += DTF * mu_t[k] * (dvy_x + dvx_y);
        }
        __syncthreads();

        // P4: publish my 4-wide stress ring to global (neighbors read next step)
        #pragma unroll
        for (int k = 0; k < KT; ++k) {
            if (!((ringm >> k) & 1)) continue;
            int si = sidx_t[k], gi = gidx_t[k];
            #pragma unroll
            for (int f = 0; f < 3; ++f)
                gstr[(f * NS + shot) * NCELL + gi] = sS[f][si];
        }

        gsync(bcnt, bgen);
    }
}

extern "C" void kernel_launch(void* const* d_in, const int* in_sizes, int n_in,
                              void* d_out, int out_size, void* d_ws, size_t ws_size,
                              hipStream_t stream) {
    const float* lamb    = (const float*)d_in[0];
    const float* mu      = (const float*)d_in[1];
    const float* buoy    = (const float*)d_in[2];
    const float* amps    = (const float*)d_in[3];
    const int*   src_loc = (const int*)d_in[4];
    const int*   rec_loc = (const int*)d_in[5];
    float* ws  = (float*)d_ws;
    float* out = (float*)d_out;

    // zero max-vel scalar + barrier counter/generation
    hipMemsetAsync(ws + SIG_OFF, 0, 96 * sizeof(float), stream);

    elastic_fused<<<NBLK, NTHR, 0, stream>>>(lamb, mu, buoy, amps, src_loc, rec_loc, out, ws);
}

// Round 5
// 473.167 us; speedup vs baseline: 6.3381x; 2.2173x over previous
//
#include <hip/hip_runtime.h>
#include <math.h>

// ---- problem constants (match reference) ----
static constexpr int NYI  = 256;
static constexpr int PMLW = 20;
static constexpr int NY   = 296, NX = 296;
static constexpr int NCELL = NY * NX;
static constexpr int NS   = 2;
static constexpr int NSRC = 8;
static constexpr int NREC = 64;
static constexpr int NT   = 64;
static constexpr float DXF = 4.0f;
static constexpr float DTF = 5e-4f;
static constexpr float FC1 = 9.0f / 8.0f;
static constexpr float FC2 = -1.0f / 24.0f;
static constexpr float INV_DX = 1.0f / DXF;

// ---- decomposition: 8x8 tiles of 37x37, one shot per block ----
static constexpr int TB = 8, TS = 37;          // 8*37 = 296 exactly
static constexpr int VS = TS + 4;              // 41: vel region (tile+2 halo, redundant)
static constexpr int SS = TS + 8;              // 45: stress region (tile+4 halo)
static constexpr int NBLK = TB * TB * NS;      // 128
static constexpr int NTHR = 512;
static constexpr int VAREA = VS * VS;          // 1681
static constexpr int TAREA = TS * TS;          // 1369
static constexpr int SFRAME = SS * SS - TAREA; // 656 frame cells
static constexpr int KV = 4, KT = 3;

// ---- global ws layout (floats): parity-double-buffered stress + barrier words ----
static constexpr int GSLOT   = 3 * NS * NCELL;       // one parity buffer
static constexpr int SIG_OFF = 2 * GSLOT;            // max-vel scalar (atomicMax target)
static constexpr int CNT_OFF = SIG_OFF + 32;         // monotonic arrival counter
static constexpr int GEN_OFF = SIG_OFF + 64;         // generation word

__device__ __forceinline__ float cohload(const float* p) {
    return __hip_atomic_load(p, __ATOMIC_RELAXED, __HIP_MEMORY_SCOPE_AGENT);
}
__device__ __forceinline__ void cohstore(float* p, float v) {
    __hip_atomic_store(p, v, __ATOMIC_RELAXED, __HIP_MEMORY_SCOPE_AGENT);
}

__global__ __launch_bounds__(NTHR, 1)
void elastic_fused(const float* __restrict__ lamb, const float* __restrict__ mu,
                   const float* __restrict__ buoy, const float* __restrict__ amps,
                   const int* __restrict__ src_loc, const int* __restrict__ rec_loc,
                   float* __restrict__ out, float* __restrict__ ws)
{
    __shared__ float sS[3][SS * SS];     // syy,sxy,sxx  (center computed, frame from neighbors)
    __shared__ float sV[2][VS * VS];     // vy,vx        (all computed locally, halo redundant)
    __shared__ float byt[VS], ayt[VS], bxt[VS], axt[VS];
    __shared__ float sAmp[NSRC * NT];
    __shared__ int   rcnt;
    __shared__ short rl_r[NREC];
    __shared__ int   rl_pos[NREC];

    int* bcnt = (int*)(ws + CNT_OFF);
    int* bgen = (int*)(ws + GEN_OFF);
    float* gstr = ws;

    const int tid  = threadIdx.x;
    const int shot = blockIdx.x & 1;
    const int tb   = blockIdx.x >> 1;
    const int bty  = tb >> 3, btx = tb & 7;
    const int gy0  = bty * TS, gx0 = btx * TS;

    // barrier: no cache fences. Data crossing blocks moves ONLY via sc1 (LLC-coherent)
    // loads/stores; __syncthreads drains vmcnt per wave, so all sc1 stores are at LLC
    // before the (LLC-serialized) arrival atomic. Monotonic counter: no reset races.
    int bk = 0;
    auto gsync = [&]() {
        ++bk;
        __syncthreads();
        if (threadIdx.x == 0) {
            int arrived = __hip_atomic_fetch_add(bcnt, 1, __ATOMIC_RELAXED,
                                                 __HIP_MEMORY_SCOPE_AGENT) + 1;
            if (arrived == NBLK * bk) {
                __hip_atomic_store(bgen, bk, __ATOMIC_RELAXED, __HIP_MEMORY_SCOPE_AGENT);
            } else {
                while (__hip_atomic_load(bgen, __ATOMIC_RELAXED, __HIP_MEMORY_SCOPE_AGENT) < bk)
                    __builtin_amdgcn_s_sleep(1);
            }
        }
        __syncthreads();
    };

    // ---- init: zero BOTH parity stress buffers via write-through (readable at LLC) ----
    for (int i = blockIdx.x * NTHR + tid; i < 2 * GSLOT; i += NBLK * NTHR)
        cohstore(&gstr[i], 0.0f);
    for (int i = tid; i < 3 * SS * SS; i += NTHR) ((float*)sS)[i] = 0.0f;
    for (int i = tid; i < 2 * VS * VS; i += NTHR) ((float*)sV)[i] = 0.0f;
    if (tid == 0) rcnt = 0;

    // ---- per-thread V-region slots (vel + its CPML memories, redundant halo-2) ----
    int   sidx_v[KV], vyv[KV], vxv[KV], smk[KV];
    float buo_v[KV];
    float msyyy[KV] = {0,0,0,0}, msxyx[KV] = {0,0,0,0};
    float msxyy[KV] = {0,0,0,0}, msxxx[KV] = {0,0,0,0};
    unsigned cvm = 0;
    #pragma unroll
    for (int k = 0; k < KV; ++k) {
        int vi = tid + NTHR * k;
        bool val = vi < VAREA;
        int vy_ = val ? vi / VS : 0;
        int vx_ = val ? vi - vy_ * VS : 0;
        int gy = gy0 - 2 + vy_, gx = gx0 - 2 + vx_;
        bool ing = val && gy >= 0 && gy < NY && gx >= 0 && gx < NX;
        if (ing) cvm |= 1u << k;
        vyv[k] = vy_; vxv[k] = vx_;
        sidx_v[k] = (vy_ + 2) * SS + (vx_ + 2);
        float b = 0.0f;
        if (ing) {
            int iy = min(max(gy - PMLW, 0), NYI - 1);
            int ix = min(max(gx - PMLW, 0), NYI - 1);
            b = buoy[iy * NYI + ix];
        }
        buo_v[k] = b;
        int sm = 0;
        #pragma unroll
        for (int s = 0; s < NSRC; ++s) {
            int sy = src_loc[(shot * NSRC + s) * 2 + 0] + PMLW;
            int sx = src_loc[(shot * NSRC + s) * 2 + 1] + PMLW;
            if (ing && sy == gy && sx == gx) sm |= 1 << s;
        }
        smk[k] = sm;
    }

    // ---- per-thread tile slots (stress + its CPML memories, owned) ----
    int   sidx_t[KT], vidx_t[KT], gidx_t[KT], tyt[KT], txt[KT];
    float lam_t[KT], mu_t[KT], l2m_t[KT];
    float mvyy[KT] = {0,0,0}, mvxx[KT] = {0,0,0}, mvyx[KT] = {0,0,0}, mvxy[KT] = {0,0,0};
    unsigned ctm = 0, ringm = 0;
    float vmax = 0.0f;
    #pragma unroll
    for (int k = 0; k < KT; ++k) {
        int ti = tid + NTHR * k;
        bool val = ti < TAREA;
        int ty = val ? ti / TS : 0;
        int tx = val ? ti - ty * TS : 0;
        int gy = gy0 + ty, gx = gx0 + tx;
        if (val) ctm |= 1u << k;
        if (val && (ty < 4 || ty >= TS - 4 || tx < 4 || tx >= TS - 4)) ringm |= 1u << k;
        tyt[k] = ty; txt[k] = tx;
        sidx_t[k] = (ty + 4) * SS + (tx + 4);
        vidx_t[k] = (ty + 2) * VS + (tx + 2);
        gidx_t[k] = gy * NX + gx;
        float la = 0.0f, m = 0.0f;
        if (val) {
            int iy = min(max(gy - PMLW, 0), NYI - 1);
            int ix = min(max(gx - PMLW, 0), NYI - 1);
            la = lamb[iy * NYI + ix];
            m  = mu  [iy * NYI + ix];
            float b = buoy[iy * NYI + ix];
            vmax = fmaxf(vmax, sqrtf((la + 2.0f * m) * b));
        }
        lam_t[k] = la; mu_t[k] = m; l2m_t[k] = la + 2.0f * m;
    }
    // grid max wave speed (device-scope atomic -> LLC, coherent)
    #pragma unroll
    for (int off = 32; off > 0; off >>= 1)
        vmax = fmaxf(vmax, __shfl_down(vmax, off));
    if ((tid & 63) == 0)
        atomicMax((int*)(ws + SIG_OFF), __float_as_int(vmax));

    __syncthreads();   // rcnt=0 + LDS zeros visible in-block
    if (tid < NREC) {
        int r = tid;
        int ry = rec_loc[(shot * NREC + r) * 2 + 0] + PMLW;
        int rx = rec_loc[(shot * NREC + r) * 2 + 1] + PMLW;
        if (ry >= gy0 && ry < gy0 + TS && rx >= gx0 && rx < gx0 + TS) {
            int p = atomicAdd(&rcnt, 1);
            rl_r[p]   = (short)r;
            rl_pos[p] = (ry - gy0 + 2) * VS + (rx - gx0 + 2);
        }
    }
    for (int i = tid; i < NSRC * NT; i += NTHR)
        sAmp[i] = amps[shot * NSRC * NT + i];

    gsync();   // global zeros + vmax at LLC, visible everywhere

    const float max_vel = __int_as_float(
        __hip_atomic_load((int*)(ws + SIG_OFF), __ATOMIC_RELAXED, __HIP_MEMORY_SCOPE_AGENT));
    const float sig_max = 3.0f * max_vel * logf(1000.0f) / (2.0f * PMLW * DXF);
    if (tid < VS) {
        auto prof = [&](int g) -> float {
            float fi = (float)g;
            float d1 = fmaxf((float)PMLW - fi, 0.0f);
            float d2 = fmaxf(fi - (float)(NY - 1 - PMLW), 0.0f);
            float dd = fmaxf(d1, d2) * (1.0f / (float)PMLW);
            return expf(-(sig_max * dd * dd) * DTF);
        };
        float b = prof(gy0 - 2 + tid); byt[tid] = b; ayt[tid] = b - 1.0f;
        b = prof(gx0 - 2 + tid);       bxt[tid] = b; axt[tid] = b - 1.0f;
    }
    __syncthreads();

    // ================= time loop: ONE grid barrier per step =================
    for (int t = 0; t < NT; ++t) {
        // parity double-buffer: read neighbors' state(t-1), write state(t)
        const float* gsr = gstr + ((t + 1) & 1) * GSLOT;
        float*       gsw = gstr + (t & 1) * GSLOT;

        // P1: load stress frame (neighbor ring strips) from LLC into sS frame
        #pragma unroll
        for (int k = 0; k < 2; ++k) {
            int ff = tid + NTHR * k;
            if (ff < SFRAME) {
                int fy, fx;
                if (ff < 4 * SS)      { fy = ff / SS;                 fx = ff - fy * SS; }
                else if (ff < 8 * SS) { int r = ff - 4 * SS; fy = SS - 4 + r / SS; fx = r % SS; }
                else {
                    int r = ff - 8 * SS;
                    if (r < (SS - 8) * 4) { fy = 4 + (r >> 2); fx = r & 3; }
                    else { r -= (SS - 8) * 4; fy = 4 + (r >> 2); fx = SS - 4 + (r & 3); }
                }
                int gy = gy0 - 4 + fy, gx = gx0 - 4 + fx;
                bool in = gy >= 0 && gy < NY && gx >= 0 && gx < NX;
                int gi = gy * NX + gx;
                #pragma unroll
                for (int f = 0; f < 3; ++f)
                    sS[f][fy * SS + fx] = in ? cohload(&gsr[(f * NS + shot) * NCELL + gi]) : 0.0f;
            }
        }
        __syncthreads();

        // P2: velocity on V (tile + redundant 2-halo)
        #pragma unroll
        for (int k = 0; k < KV; ++k) {
            if (!((cvm >> k) & 1)) continue;
            int si = sidx_v[k];
            float by_ = byt[vyv[k]], ay_ = ayt[vyv[k]];
            float bx_ = bxt[vxv[k]], ax_ = axt[vxv[k]];
            float d, mm;
            d = (FC1 * (sS[0][si] - sS[0][si - SS]) + FC2 * (sS[0][si + SS] - sS[0][si - 2 * SS])) * INV_DX;
            mm = by_ * msyyy[k] + ay_ * d;  msyyy[k] = mm;  float dsyy_y = d + mm;
            d = (FC1 * (sS[1][si] - sS[1][si - 1]) + FC2 * (sS[1][si + 1] - sS[1][si - 2])) * INV_DX;
            mm = bx_ * msxyx[k] + ax_ * d;  msxyx[k] = mm;  float dsxy_x = d + mm;
            d = (FC1 * (sS[1][si] - sS[1][si - SS]) + FC2 * (sS[1][si + SS] - sS[1][si - 2 * SS])) * INV_DX;
            mm = by_ * msxyy[k] + ay_ * d;  msxyy[k] = mm;  float dsxy_y = d + mm;
            d = (FC1 * (sS[2][si] - sS[2][si - 1]) + FC2 * (sS[2][si + 1] - sS[2][si - 2])) * INV_DX;
            mm = bx_ * msxxx[k] + ax_ * d;  msxxx[k] = mm;  float dsxx_x = d + mm;
            int vi = tid + NTHR * k;
            float nvy = sV[0][vi] + DTF * buo_v[k] * (dsyy_y + dsxy_x);
            float nvx = sV[1][vi] + DTF * buo_v[k] * (dsxy_y + dsxx_x);
            if (smk[k]) {
                #pragma unroll
                for (int s = 0; s < NSRC; ++s)
                    if ((smk[k] >> s) & 1) nvy += DTF * buo_v[k] * sAmp[s * NT + t];
            }
            sV[0][vi] = nvy;
            sV[1][vi] = nvx;
        }
        __syncthreads();

        // receivers: vy after injection (LDS-resident; plain store, flushed at kernel end)
        if (tid < rcnt)
            out[(shot * NREC + rl_r[tid]) * NT + t] = sV[0][rl_pos[tid]];

        // P3: stress on tile (reads only sV; writes own sS center cell)
        #pragma unroll
        for (int k = 0; k < KT; ++k) {
            if (!((ctm >> k) & 1)) continue;
            int si = sidx_t[k], vi = vidx_t[k];
            float by_ = byt[tyt[k] + 2], ay_ = ayt[tyt[k] + 2];
            float bx_ = bxt[txt[k] + 2], ax_ = axt[txt[k] + 2];
            float d, mm;
            d = (FC1 * (sV[0][vi + VS] - sV[0][vi]) + FC2 * (sV[0][vi + 2 * VS] - sV[0][vi - VS])) * INV_DX;
            mm = by_ * mvyy[k] + ay_ * d;  mvyy[k] = mm;  float dvy_y = d + mm;
            d = (FC1 * (sV[1][vi + 1] - sV[1][vi]) + FC2 * (sV[1][vi + 2] - sV[1][vi - 1])) * INV_DX;
            mm = bx_ * mvxx[k] + ax_ * d;  mvxx[k] = mm;  float dvx_x = d + mm;
            sS[0][si] += DTF * (l2m_t[k] * dvy_y + lam_t[k] * dvx_x);
            sS[2][si] += DTF * (lam_t[k] * dvy_y + l2m_t[k] * dvx_x);
            d = (FC1 * (sV[0][vi + 1] - sV[0][vi]) + FC2 * (sV[0][vi + 2] - sV[0][vi - 1])) * INV_DX;
            mm = bx_ * mvyx[k] + ax_ * d;  mvyx[k] = mm;  float dvy_x = d + mm;
            d = (FC1 * (sV[1][vi + VS] - sV[1][vi]) + FC2 * (sV[1][vi + 2 * VS] - sV[1][vi - VS])) * INV_DX;
            mm = by_ * mvxy[k] + ay_ * d;  mvxy[k] = mm;  float dvx_y = d + mm;
            sS[1][si] += DTF * mu_t[k] * (dvy_x + dvx_y);
        }
        __syncthreads();

        // P4: publish my 4-wide stress ring write-through to LLC (parity t&1)
        #pragma unroll
        for (int k = 0; k < KT; ++k) {
            if (!((ringm >> k) & 1)) continue;
            int si = sidx_t[k], gi = gidx_t[k];
            #pragma unroll
            for (int f = 0; f < 3; ++f)
                cohstore(&gsw[(f * NS + shot) * NCELL + gi], sS[f][si]);
        }

        gsync();
    }
}

extern "C" void kernel_launch(void* const* d_in, const int* in_sizes, int n_in,
                              void* d_out, int out_size, void* d_ws, size_t ws_size,
                              hipStream_t stream) {
    const float* lamb    = (const float*)d_in[0];
    const float* mu      = (const float*)d_in[1];
    const float* buoy    = (const float*)d_in[2];
    const float* amps    = (const float*)d_in[3];
    const int*   src_loc = (const int*)d_in[4];
    const int*   rec_loc = (const int*)d_in[5];
    float* ws  = (float*)d_ws;
    float* out = (float*)d_out;

    // zero max-vel scalar + barrier counter/generation
    hipMemsetAsync(ws + SIG_OFF, 0, 96 * sizeof(float), stream);

    elastic_fused<<<NBLK, NTHR, 0, stream>>>(lamb, mu, buoy, amps, src_loc, rec_loc, out, ws);
}

// Round 6
// 399.732 us; speedup vs baseline: 7.5025x; 1.1837x over previous
//
#include <hip/hip_runtime.h>
#include <math.h>

// ---- problem constants (match reference) ----
static constexpr int NYI  = 256;
static constexpr int PMLW = 20;
static constexpr int NY   = 296, NX = 296;
static constexpr int NCELL = NY * NX;
static constexpr int NS   = 2;
static constexpr int NSRC = 8;
static constexpr int NREC = 64;
static constexpr int NT   = 64;
static constexpr float DXF = 4.0f;
static constexpr float DTF = 5e-4f;
static constexpr float FC1 = 9.0f / 8.0f;
static constexpr float FC2 = -1.0f / 24.0f;
static constexpr float INV_DX = 1.0f / DXF;

// ---- decomposition: 8x8 tiles of 37x37, one shot per block ----
static constexpr int TB = 8, TS = 37;          // 8*37 = 296 exactly
static constexpr int VS = TS + 4;              // 41: vel region (tile+2 halo, redundant)
static constexpr int SS = TS + 8;              // 45: stress region (tile+4 halo)
static constexpr int NBLK = TB * TB * NS;      // 128
static constexpr int NTHR = 512;
static constexpr int VAREA = VS * VS;          // 1681
static constexpr int TAREA = TS * TS;          // 1369
static constexpr int SFRAME = SS * SS - TAREA; // 656 frame cells
static constexpr int KV = 4, KT = 3;

// ---- global ws layout (floats): parity-double-buffered stress + barrier words ----
static constexpr int GSLOT   = 3 * NS * NCELL;       // one parity buffer
static constexpr int SIG_OFF = 2 * GSLOT;            // max-vel scalar (atomicMax target)
static constexpr int CNT_OFF = SIG_OFF + 32;         // monotonic arrival counter
static constexpr int GEN_OFF = SIG_OFF + 64;         // generation word

__device__ __forceinline__ float cohload(const float* p) {
    return __hip_atomic_load(p, __ATOMIC_RELAXED, __HIP_MEMORY_SCOPE_AGENT);
}
__device__ __forceinline__ void cohstore(float* p, float v) {
    __hip_atomic_store(p, v, __ATOMIC_RELAXED, __HIP_MEMORY_SCOPE_AGENT);
}

__global__ __launch_bounds__(NTHR, 1)
void elastic_fused(const float* __restrict__ lamb, const float* __restrict__ mu,
                   const float* __restrict__ buoy, const float* __restrict__ amps,
                   const int* __restrict__ src_loc, const int* __restrict__ rec_loc,
                   float* __restrict__ out, float* __restrict__ ws)
{
    __shared__ float sS[3][SS * SS];     // syy,sxy,sxx  (center computed, frame from neighbors)
    __shared__ float sV[2][VS * VS];     // vy,vx        (all computed locally, halo redundant)
    __shared__ float byt[VS], ayt[VS], bxt[VS], axt[VS];
    __shared__ float sAmp[NSRC * NT];
    __shared__ int   rcnt;
    __shared__ short rl_r[NREC];
    __shared__ int   rl_pos[NREC];

    int* bcnt = (int*)(ws + CNT_OFF);
    int* bgen = (int*)(ws + GEN_OFF);
    float* gstr = ws;

    const int tid  = threadIdx.x;
    const int shot = blockIdx.x & 1;
    const int tb   = blockIdx.x >> 1;
    const int bty  = tb >> 3, btx = tb & 7;
    const int gy0  = bty * TS, gx0 = btx * TS;

    // split barrier: arrive right after publishing; wait as late as possible.
    // Monotonic counter, generation word; all traffic sc1 (LLC-coherent), no cache fences.
    // __syncthreads before the arrival atomic -> each wave drained vmcnt (stores at LLC).
    int bk = 0;
    auto arrive = [&]() {
        ++bk;
        __syncthreads();
        if (tid == 0) {
            int n = __hip_atomic_fetch_add(bcnt, 1, __ATOMIC_RELAXED,
                                           __HIP_MEMORY_SCOPE_AGENT) + 1;
            if (n == NBLK * bk)
                __hip_atomic_store(bgen, bk, __ATOMIC_RELAXED, __HIP_MEMORY_SCOPE_AGENT);
        }
    };
    auto wait = [&]() {
        if (tid == 0) {
            while (__hip_atomic_load(bgen, __ATOMIC_RELAXED, __HIP_MEMORY_SCOPE_AGENT) < bk)
                __builtin_amdgcn_s_sleep(1);
        }
        __syncthreads();
    };

    // ---- zero LDS fields (global stress buffers need NO init: t==0 frame forced 0) ----
    for (int i = tid; i < 3 * SS * SS; i += NTHR) ((float*)sS)[i] = 0.0f;
    for (int i = tid; i < 2 * VS * VS; i += NTHR) ((float*)sV)[i] = 0.0f;
    if (tid == 0) rcnt = 0;

    // ---- per-thread V-region slots (vel + its CPML memories, redundant halo-2) ----
    int   sidx_v[KV], vyv[KV], vxv[KV], smk[KV];
    float buo_v[KV];
    float msyyy[KV] = {0,0,0,0}, msxyx[KV] = {0,0,0,0};
    float msxyy[KV] = {0,0,0,0}, msxxx[KV] = {0,0,0,0};
    unsigned cvm = 0, intm = 0;
    #pragma unroll
    for (int k = 0; k < KV; ++k) {
        int vi = tid + NTHR * k;
        bool val = vi < VAREA;
        int vy_ = val ? vi / VS : 0;
        int vx_ = val ? vi - vy_ * VS : 0;
        int gy = gy0 - 2 + vy_, gx = gx0 - 2 + vx_;
        bool ing = val && gy >= 0 && gy < NY && gx >= 0 && gx < NX;
        if (ing) cvm |= 1u << k;
        // interior: stencil S-rows [vy,vy+3], S-cols [vx,vx+3] all inside [4,41)
        if (ing && vy_ >= 4 && vy_ <= 37 && vx_ >= 4 && vx_ <= 37) intm |= 1u << k;
        vyv[k] = vy_; vxv[k] = vx_;
        sidx_v[k] = (vy_ + 2) * SS + (vx_ + 2);
        float b = 0.0f;
        if (ing) {
            int iy = min(max(gy - PMLW, 0), NYI - 1);
            int ix = min(max(gx - PMLW, 0), NYI - 1);
            b = buoy[iy * NYI + ix];
        }
        buo_v[k] = b;
        int sm = 0;
        #pragma unroll
        for (int s = 0; s < NSRC; ++s) {
            int sy = src_loc[(shot * NSRC + s) * 2 + 0] + PMLW;
            int sx = src_loc[(shot * NSRC + s) * 2 + 1] + PMLW;
            if (ing && sy == gy && sx == gx) sm |= 1 << s;
        }
        smk[k] = sm;
    }
    const unsigned bndm = cvm & ~intm;

    // ---- per-thread tile slots (stress + its CPML memories, owned) ----
    int   sidx_t[KT], vidx_t[KT], gidx_t[KT], tyt[KT], txt[KT];
    float lam_t[KT], mu_t[KT], l2m_t[KT];
    float mvyy[KT] = {0,0,0}, mvxx[KT] = {0,0,0}, mvyx[KT] = {0,0,0}, mvxy[KT] = {0,0,0};
    unsigned ctm = 0, ringm = 0;
    float vmax = 0.0f;
    #pragma unroll
    for (int k = 0; k < KT; ++k) {
        int ti = tid + NTHR * k;
        bool val = ti < TAREA;
        int ty = val ? ti / TS : 0;
        int tx = val ? ti - ty * TS : 0;
        int gy = gy0 + ty, gx = gx0 + tx;
        if (val) ctm |= 1u << k;
        if (val && (ty < 4 || ty >= TS - 4 || tx < 4 || tx >= TS - 4)) ringm |= 1u << k;
        tyt[k] = ty; txt[k] = tx;
        sidx_t[k] = (ty + 4) * SS + (tx + 4);
        vidx_t[k] = (ty + 2) * VS + (tx + 2);
        gidx_t[k] = gy * NX + gx;
        float la = 0.0f, m = 0.0f;
        if (val) {
            int iy = min(max(gy - PMLW, 0), NYI - 1);
            int ix = min(max(gx - PMLW, 0), NYI - 1);
            la = lamb[iy * NYI + ix];
            m  = mu  [iy * NYI + ix];
            float b = buoy[iy * NYI + ix];
            vmax = fmaxf(vmax, sqrtf((la + 2.0f * m) * b));
        }
        lam_t[k] = la; mu_t[k] = m; l2m_t[k] = la + 2.0f * m;
    }
    // grid max wave speed
    #pragma unroll
    for (int off = 32; off > 0; off >>= 1)
        vmax = fmaxf(vmax, __shfl_down(vmax, off));
    if ((tid & 63) == 0)
        atomicMax((int*)(ws + SIG_OFF), __float_as_int(vmax));

    // ---- per-thread frame-slot geometry (precomputed; P1 becomes pure loads) ----
    bool fval[2], fin[2];
    int  flidx[2], fgi[2];
    #pragma unroll
    for (int k = 0; k < 2; ++k) {
        int ff = tid + NTHR * k;
        fval[k] = ff < SFRAME;
        int fy = 0, fx = 0;
        if (fval[k]) {
            if (ff < 4 * SS)      { fy = ff / SS;                 fx = ff - fy * SS; }
            else if (ff < 8 * SS) { int r = ff - 4 * SS; fy = SS - 4 + r / SS; fx = r % SS; }
            else {
                int r = ff - 8 * SS;
                if (r < (SS - 8) * 4) { fy = 4 + (r >> 2); fx = r & 3; }
                else { r -= (SS - 8) * 4; fy = 4 + (r >> 2); fx = SS - 4 + (r & 3); }
            }
        }
        int gy = gy0 - 4 + fy, gx = gx0 - 4 + fx;
        fin[k]   = fval[k] && gy >= 0 && gy < NY && gx >= 0 && gx < NX;
        flidx[k] = fy * SS + fx;
        fgi[k]   = fin[k] ? (gy * NX + gx) : 0;
    }

    __syncthreads();   // rcnt=0 + LDS zeros visible in-block
    if (tid < NREC) {
        int r = tid;
        int ry = rec_loc[(shot * NREC + r) * 2 + 0] + PMLW;
        int rx = rec_loc[(shot * NREC + r) * 2 + 1] + PMLW;
        if (ry >= gy0 && ry < gy0 + TS && rx >= gx0 && rx < gx0 + TS) {
            int p = atomicAdd(&rcnt, 1);
            rl_r[p]   = (short)r;
            rl_pos[p] = (ry - gy0 + 2) * VS + (rx - gx0 + 2);
        }
    }
    for (int i = tid; i < NSRC * NT; i += NTHR)
        sAmp[i] = amps[shot * NSRC * NT + i];

    arrive(); wait();   // vmax at LLC, visible everywhere

    const float max_vel = __int_as_float(
        __hip_atomic_load((int*)(ws + SIG_OFF), __ATOMIC_RELAXED, __HIP_MEMORY_SCOPE_AGENT));
    const float sig_max = 3.0f * max_vel * logf(1000.0f) / (2.0f * PMLW * DXF);
    if (tid < VS) {
        auto prof = [&](int g) -> float {
            float fi = (float)g;
            float d1 = fmaxf((float)PMLW - fi, 0.0f);
            float d2 = fmaxf(fi - (float)(NY - 1 - PMLW), 0.0f);
            float dd = fmaxf(d1, d2) * (1.0f / (float)PMLW);
            return expf(-(sig_max * dd * dd) * DTF);
        };
        float b = prof(gy0 - 2 + tid); byt[tid] = b; ayt[tid] = b - 1.0f;
        b = prof(gx0 - 2 + tid);       bxt[tid] = b; axt[tid] = b - 1.0f;
    }
    __syncthreads();

    // velocity body over a slot mask (interior runs pre-wait, boundary post-frame-fill)
    auto do_vel = [&](unsigned m, int t) {
        #pragma unroll
        for (int k = 0; k < KV; ++k) {
            if (!((m >> k) & 1)) continue;
            int si = sidx_v[k];
            float by_ = byt[vyv[k]], ay_ = ayt[vyv[k]];
            float bx_ = bxt[vxv[k]], ax_ = axt[vxv[k]];
            float d, mm;
            d = (FC1 * (sS[0][si] - sS[0][si - SS]) + FC2 * (sS[0][si + SS] - sS[0][si - 2 * SS])) * INV_DX;
            mm = by_ * msyyy[k] + ay_ * d;  msyyy[k] = mm;  float dsyy_y = d + mm;
            d = (FC1 * (sS[1][si] - sS[1][si - 1]) + FC2 * (sS[1][si + 1] - sS[1][si - 2])) * INV_DX;
            mm = bx_ * msxyx[k] + ax_ * d;  msxyx[k] = mm;  float dsxy_x = d + mm;
            d = (FC1 * (sS[1][si] - sS[1][si - SS]) + FC2 * (sS[1][si + SS] - sS[1][si - 2 * SS])) * INV_DX;
            mm = by_ * msxyy[k] + ay_ * d;  msxyy[k] = mm;  float dsxy_y = d + mm;
            d = (FC1 * (sS[2][si] - sS[2][si - 1]) + FC2 * (sS[2][si + 1] - sS[2][si - 2])) * INV_DX;
            mm = bx_ * msxxx[k] + ax_ * d;  msxxx[k] = mm;  float dsxx_x = d + mm;
            int vi = tid + NTHR * k;
            float nvy = sV[0][vi] + DTF * buo_v[k] * (dsyy_y + dsxy_x);
            float nvx = sV[1][vi] + DTF * buo_v[k] * (dsxy_y + dsxx_x);
            if (smk[k]) {
                #pragma unroll
                for (int s = 0; s < NSRC; ++s)
                    if ((smk[k] >> s) & 1) nvy += DTF * buo_v[k] * sAmp[s * NT + t];
            }
            sV[0][vi] = nvy;
            sV[1][vi] = nvx;
        }
    };

    // ================= time loop: ONE grid barrier per step =================
    for (int t = 0; t < NT; ++t) {
        const float* gsr = gstr + ((t + 1) & 1) * GSLOT;   // neighbors' state(t-1)
        float*       gsw = gstr + (t & 1) * GSLOT;         // my state(t)

        // interior velocity: no frame dependency -> overlaps other blocks' arrival/wake
        do_vel(intm, t);

        wait();   // neighbors' ring(t-1) at LLC, visible

        // P1: frame loads (6 sc1 loads, clustered) -> LDS frame
        float fr0[3], fr1[3];
        #pragma unroll
        for (int f = 0; f < 3; ++f) {
            fr0[f] = (t > 0 && fin[0]) ? cohload(&gsr[(f * NS + shot) * NCELL + fgi[0]]) : 0.0f;
            fr1[f] = (t > 0 && fin[1]) ? cohload(&gsr[(f * NS + shot) * NCELL + fgi[1]]) : 0.0f;
        }
        if (fval[0]) { sS[0][flidx[0]] = fr0[0]; sS[1][flidx[0]] = fr0[1]; sS[2][flidx[0]] = fr0[2]; }
        if (fval[1]) { sS[0][flidx[1]] = fr1[0]; sS[1][flidx[1]] = fr1[1]; sS[2][flidx[1]] = fr1[2]; }
        __syncthreads();

        // boundary velocity (needs frame)
        do_vel(bndm, t);
        __syncthreads();

        // receivers: vy after injection (LDS-resident)
        if (tid < rcnt)
            out[(shot * NREC + rl_r[tid]) * NT + t] = sV[0][rl_pos[tid]];

        // P3+P4 fused: stress on tile; ring cells published immediately (same thread owns both)
        #pragma unroll
        for (int k = 0; k < KT; ++k) {
            if (!((ctm >> k) & 1)) continue;
            int si = sidx_t[k], vi = vidx_t[k];
            float by_ = byt[tyt[k] + 2], ay_ = ayt[tyt[k] + 2];
            float bx_ = bxt[txt[k] + 2], ax_ = axt[txt[k] + 2];
            float d, mm;
            d = (FC1 * (sV[0][vi + VS] - sV[0][vi]) + FC2 * (sV[0][vi + 2 * VS] - sV[0][vi - VS])) * INV_DX;
            mm = by_ * mvyy[k] + ay_ * d;  mvyy[k] = mm;  float dvy_y = d + mm;
            d = (FC1 * (sV[1][vi + 1] - sV[1][vi]) + FC2 * (sV[1][vi + 2] - sV[1][vi - 1])) * INV_DX;
            mm = bx_ * mvxx[k] + ax_ * d;  mvxx[k] = mm;  float dvx_x = d + mm;
            float nsyy = sS[0][si] + DTF * (l2m_t[k] * dvy_y + lam_t[k] * dvx_x);
            float nsxx = sS[2][si] + DTF * (lam_t[k] * dvy_y + l2m_t[k] * dvx_x);
            d = (FC1 * (sV[0][vi + 1] - sV[0][vi]) + FC2 * (sV[0][vi + 2] - sV[0][vi - 1])) * INV_DX;
            mm = bx_ * mvyx[k] + ax_ * d;  mvyx[k] = mm;  float dvy_x = d + mm;
            d = (FC1 * (sV[1][vi + VS] - sV[1][vi]) + FC2 * (sV[1][vi + 2 * VS] - sV[1][vi - VS])) * INV_DX;
            mm = by_ * mvxy[k] + ay_ * d;  mvxy[k] = mm;  float dvx_y = d + mm;
            float nsxy = sS[1][si] + DTF * mu_t[k] * (dvy_x + dvx_y);
            sS[0][si] = nsyy; sS[1][si] = nsxy; sS[2][si] = nsxx;
            if ((ringm >> k) & 1) {
                int gi = gidx_t[k];
                cohstore(&gsw[(0 * NS + shot) * NCELL + gi], nsyy);
                cohstore(&gsw[(1 * NS + shot) * NCELL + gi], nsxy);
                cohstore(&gsw[(2 * NS + shot) * NCELL + gi], nsxx);
            }
        }

        // arrive (syncthreads drains ring stores; also orders sS writes vs next interior read)
        if (t < NT - 1) arrive();
    }
}

extern "C" void kernel_launch(void* const* d_in, const int* in_sizes, int n_in,
                              void* d_out, int out_size, void* d_ws, size_t ws_size,
                              hipStream_t stream) {
    const float* lamb    = (const float*)d_in[0];
    const float* mu      = (const float*)d_in[1];
    const float* buoy    = (const float*)d_in[2];
    const float* amps    = (const float*)d_in[3];
    const int*   src_loc = (const int*)d_in[4];
    const int*   rec_loc = (const int*)d_in[5];
    float* ws  = (float*)d_ws;
    float* out = (float*)d_out;

    // zero max-vel scalar + barrier counter/generation
    hipMemsetAsync(ws + SIG_OFF, 0, 96 * sizeof(float), stream);

    elastic_fused<<<NBLK, NTHR, 0, stream>>>(lamb, mu, buoy, amps, src_loc, rec_loc, out, ws);
}

// Round 7
// 339.674 us; speedup vs baseline: 8.8291x; 1.1768x over previous
//
#include <hip/hip_runtime.h>
#include <math.h>

// ---- problem constants (match reference) ----
static constexpr int NYI  = 256;
static constexpr int PMLW = 20;
static constexpr int NY   = 296, NX = 296;
static constexpr int NCELL = NY * NX;
static constexpr int NS   = 2;
static constexpr int NSRC = 8;
static constexpr int NREC = 64;
static constexpr int NT   = 64;
static constexpr float DXF = 4.0f;
static constexpr float DTF = 5e-4f;
static constexpr float FC1 = 9.0f / 8.0f;
static constexpr float FC2 = -1.0f / 24.0f;
static constexpr float INV_DX = 1.0f / DXF;

// ---- decomposition: 8x8 tiles of 37x37, one shot per block ----
static constexpr int TB = 8, TS = 37;          // 8*37 = 296 exactly
static constexpr int VS = TS + 4;              // 41: vel region (tile+2 halo, redundant)
static constexpr int SS = TS + 8;              // 45: stress region (tile+4 halo)
static constexpr int NBLK = TB * TB * NS;      // 128
static constexpr int NTHR = 512;
static constexpr int VAREA = VS * VS;          // 1681
static constexpr int TAREA = TS * TS;          // 1369
static constexpr int SFRAME = SS * SS - TAREA; // 656 frame cells
static constexpr int KV = 4, KT = 3;

// ---- global ws layout (floats): parity-double-buffered stress + per-block flags ----
static constexpr int GSLOT   = 3 * NS * NCELL;       // one parity buffer
static constexpr int FLG_OFF = 2 * GSLOT;            // int flags[NBLK]: steps published

__device__ __forceinline__ float cohload(const float* p) {
    return __hip_atomic_load(p, __ATOMIC_RELAXED, __HIP_MEMORY_SCOPE_AGENT);
}
__device__ __forceinline__ void cohstore(float* p, float v) {
    __hip_atomic_store(p, v, __ATOMIC_RELAXED, __HIP_MEMORY_SCOPE_AGENT);
}

__global__ __launch_bounds__(NTHR, 1)
void elastic_fused(const float* __restrict__ lamb, const float* __restrict__ mu,
                   const float* __restrict__ buoy, const float* __restrict__ amps,
                   const int* __restrict__ src_loc, const int* __restrict__ rec_loc,
                   float* __restrict__ out, float* __restrict__ ws)
{
    __shared__ float sS[3][SS * SS];     // syy,sxy,sxx  (center computed, frame from neighbors)
    __shared__ float sV[2][VS * VS];     // vy,vx        (all computed locally, halo redundant)
    __shared__ float byt[VS], ayt[VS], bxt[VS], axt[VS];
    __shared__ float sAmp[NSRC * NT];
    __shared__ float wmax[NTHR / 64];
    __shared__ int   rcnt;
    __shared__ short rl_r[NREC];
    __shared__ int   rl_pos[NREC];

    int* flags = (int*)(ws + FLG_OFF);
    float* gstr = ws;

    const int tid  = threadIdx.x;
    const int shot = blockIdx.x & 1;
    const int tb   = blockIdx.x >> 1;
    const int bty  = tb >> 3, btx = tb & 7;
    const int gy0  = bty * TS, gx0 = btx * TS;
    const int myBlk = blockIdx.x;

    // poll thread -> one spatial neighbor (same shot); frame touches corners, so all 8
    int myNbr = -1;
    if (tid < 8) {
        int idx = tid < 4 ? tid : tid + 1;          // skip center of 3x3
        int dy = idx / 3 - 1, dx = idx % 3 - 1;
        int nty = bty + dy, ntx = btx + dx;
        if (nty >= 0 && nty < TB && ntx >= 0 && ntx < TB)
            myNbr = ((nty * TB + ntx) << 1) | shot;
    }

    // ---- zero LDS fields (global stress buffers need NO init: t==0 frame forced 0) ----
    for (int i = tid; i < 3 * SS * SS; i += NTHR) ((float*)sS)[i] = 0.0f;
    for (int i = tid; i < 2 * VS * VS; i += NTHR) ((float*)sV)[i] = 0.0f;
    if (tid == 0) rcnt = 0;

    // ---- block-local global max wave speed: scan full interior (bit-identical per block;
    //      max is order-free, sqrt monotone => sqrt(max) == max(sqrt)) ----
    float vmax = 0.0f;
    for (int i = tid * 4; i < NYI * NYI; i += NTHR * 4) {
        const float4 la4 = *(const float4*)(lamb + i);
        const float4 mu4 = *(const float4*)(mu + i);
        const float4 b4  = *(const float4*)(buoy + i);
        vmax = fmaxf(vmax, (la4.x + 2.0f * mu4.x) * b4.x);
        vmax = fmaxf(vmax, (la4.y + 2.0f * mu4.y) * b4.y);
        vmax = fmaxf(vmax, (la4.z + 2.0f * mu4.z) * b4.z);
        vmax = fmaxf(vmax, (la4.w + 2.0f * mu4.w) * b4.w);
    }
    #pragma unroll
    for (int off = 32; off > 0; off >>= 1)
        vmax = fmaxf(vmax, __shfl_down(vmax, off));
    if ((tid & 63) == 0) wmax[tid >> 6] = vmax;

    // ---- per-thread V-region slots (vel + its CPML memories, redundant halo-2) ----
    int   sidx_v[KV], vyv[KV], vxv[KV], smk[KV];
    float buo_v[KV];
    float msyyy[KV] = {0,0,0,0}, msxyx[KV] = {0,0,0,0};
    float msxyy[KV] = {0,0,0,0}, msxxx[KV] = {0,0,0,0};
    unsigned cvm = 0, intm = 0;
    #pragma unroll
    for (int k = 0; k < KV; ++k) {
        int vi = tid + NTHR * k;
        bool val = vi < VAREA;
        int vy_ = val ? vi / VS : 0;
        int vx_ = val ? vi - vy_ * VS : 0;
        int gy = gy0 - 2 + vy_, gx = gx0 - 2 + vx_;
        bool ing = val && gy >= 0 && gy < NY && gx >= 0 && gx < NX;
        if (ing) cvm |= 1u << k;
        // interior: stencil S-rows [vy,vy+3], S-cols [vx,vx+3] all inside [4,41)
        if (ing && vy_ >= 4 && vy_ <= 37 && vx_ >= 4 && vx_ <= 37) intm |= 1u << k;
        vyv[k] = vy_; vxv[k] = vx_;
        sidx_v[k] = (vy_ + 2) * SS + (vx_ + 2);
        float b = 0.0f;
        if (ing) {
            int iy = min(max(gy - PMLW, 0), NYI - 1);
            int ix = min(max(gx - PMLW, 0), NYI - 1);
            b = buoy[iy * NYI + ix];
        }
        buo_v[k] = b;
        int sm = 0;
        #pragma unroll
        for (int s = 0; s < NSRC; ++s) {
            int sy = src_loc[(shot * NSRC + s) * 2 + 0] + PMLW;
            int sx = src_loc[(shot * NSRC + s) * 2 + 1] + PMLW;
            if (ing && sy == gy && sx == gx) sm |= 1 << s;
        }
        smk[k] = sm;
    }
    const unsigned bndm = cvm & ~intm;

    // ---- per-thread tile slots (stress + its CPML memories, owned) ----
    int   sidx_t[KT], vidx_t[KT], gidx_t[KT], tyt[KT], txt[KT];
    float lam_t[KT], mu_t[KT], l2m_t[KT];
    float mvyy[KT] = {0,0,0}, mvxx[KT] = {0,0,0}, mvyx[KT] = {0,0,0}, mvxy[KT] = {0,0,0};
    unsigned ctm = 0, ringm = 0;
    #pragma unroll
    for (int k = 0; k < KT; ++k) {
        int ti = tid + NTHR * k;
        bool val = ti < TAREA;
        int ty = val ? ti / TS : 0;
        int tx = val ? ti - ty * TS : 0;
        int gy = gy0 + ty, gx = gx0 + tx;
        if (val) ctm |= 1u << k;
        if (val && (ty < 4 || ty >= TS - 4 || tx < 4 || tx >= TS - 4)) ringm |= 1u << k;
        tyt[k] = ty; txt[k] = tx;
        sidx_t[k] = (ty + 4) * SS + (tx + 4);
        vidx_t[k] = (ty + 2) * VS + (tx + 2);
        gidx_t[k] = gy * NX + gx;
        float la = 0.0f, m = 0.0f;
        if (val) {
            int iy = min(max(gy - PMLW, 0), NYI - 1);
            int ix = min(max(gx - PMLW, 0), NYI - 1);
            la = lamb[iy * NYI + ix];
            m  = mu  [iy * NYI + ix];
        }
        lam_t[k] = la; mu_t[k] = m; l2m_t[k] = la + 2.0f * m;
    }

    // ---- per-thread frame-slot geometry (precomputed; P1 becomes pure loads) ----
    bool fval[2], fin[2];
    int  flidx[2], fgi[2];
    #pragma unroll
    for (int k = 0; k < 2; ++k) {
        int ff = tid + NTHR * k;
        fval[k] = ff < SFRAME;
        int fy = 0, fx = 0;
        if (fval[k]) {
            if (ff < 4 * SS)      { fy = ff / SS;                 fx = ff - fy * SS; }
            else if (ff < 8 * SS) { int r = ff - 4 * SS; fy = SS - 4 + r / SS; fx = r % SS; }
            else {
                int r = ff - 8 * SS;
                if (r < (SS - 8) * 4) { fy = 4 + (r >> 2); fx = r & 3; }
                else { r -= (SS - 8) * 4; fy = 4 + (r >> 2); fx = SS - 4 + (r & 3); }
            }
        }
        int gy = gy0 - 4 + fy, gx = gx0 - 4 + fx;
        fin[k]   = fval[k] && gy >= 0 && gy < NY && gx >= 0 && gx < NX;
        flidx[k] = fy * SS + fx;
        fgi[k]   = fin[k] ? (gy * NX + gx) : 0;
    }

    __syncthreads();   // wmax + LDS zeros + rcnt=0 visible in-block

    float vall = wmax[0];
    #pragma unroll
    for (int w = 1; w < NTHR / 64; ++w) vall = fmaxf(vall, wmax[w]);
    const float max_vel = sqrtf(vall);
    const float sig_max = 3.0f * max_vel * logf(1000.0f) / (2.0f * PMLW * DXF);
    if (tid < VS) {
        auto prof = [&](int g) -> float {
            float fi = (float)g;
            float d1 = fmaxf((float)PMLW - fi, 0.0f);
            float d2 = fmaxf(fi - (float)(NY - 1 - PMLW), 0.0f);
            float dd = fmaxf(d1, d2) * (1.0f / (float)PMLW);
            return expf(-(sig_max * dd * dd) * DTF);
        };
        float b = prof(gy0 - 2 + tid); byt[tid] = b; ayt[tid] = b - 1.0f;
        b = prof(gx0 - 2 + tid);       bxt[tid] = b; axt[tid] = b - 1.0f;
    }
    if (tid < NREC) {
        int r = tid;
        int ry = rec_loc[(shot * NREC + r) * 2 + 0] + PMLW;
        int rx = rec_loc[(shot * NREC + r) * 2 + 1] + PMLW;
        if (ry >= gy0 && ry < gy0 + TS && rx >= gx0 && rx < gx0 + TS) {
            int p = atomicAdd(&rcnt, 1);
            rl_r[p]   = (short)r;
            rl_pos[p] = (ry - gy0 + 2) * VS + (rx - gx0 + 2);
        }
    }
    for (int i = tid; i < NSRC * NT; i += NTHR)
        sAmp[i] = amps[shot * NSRC * NT + i];
    __syncthreads();   // tables + amps + receiver lists visible

    // velocity body over a slot mask (interior runs pre-wait, boundary post-frame-fill)
    auto do_vel = [&](unsigned m, int t) {
        #pragma unroll
        for (int k = 0; k < KV; ++k) {
            if (!((m >> k) & 1)) continue;
            int si = sidx_v[k];
            float by_ = byt[vyv[k]], ay_ = ayt[vyv[k]];
            float bx_ = bxt[vxv[k]], ax_ = axt[vxv[k]];
            float d, mm;
            d = (FC1 * (sS[0][si] - sS[0][si - SS]) + FC2 * (sS[0][si + SS] - sS[0][si - 2 * SS])) * INV_DX;
            mm = by_ * msyyy[k] + ay_ * d;  msyyy[k] = mm;  float dsyy_y = d + mm;
            d = (FC1 * (sS[1][si] - sS[1][si - 1]) + FC2 * (sS[1][si + 1] - sS[1][si - 2])) * INV_DX;
            mm = bx_ * msxyx[k] + ax_ * d;  msxyx[k] = mm;  float dsxy_x = d + mm;
            d = (FC1 * (sS[1][si] - sS[1][si - SS]) + FC2 * (sS[1][si + SS] - sS[1][si - 2 * SS])) * INV_DX;
            mm = by_ * msxyy[k] + ay_ * d;  msxyy[k] = mm;  float dsxy_y = d + mm;
            d = (FC1 * (sS[2][si] - sS[2][si - 1]) + FC2 * (sS[2][si + 1] - sS[2][si - 2])) * INV_DX;
            mm = bx_ * msxxx[k] + ax_ * d;  msxxx[k] = mm;  float dsxx_x = d + mm;
            int vi = tid + NTHR * k;
            float nvy = sV[0][vi] + DTF * buo_v[k] * (dsyy_y + dsxy_x);
            float nvx = sV[1][vi] + DTF * buo_v[k] * (dsxy_y + dsxx_x);
            if (smk[k]) {
                #pragma unroll
                for (int s = 0; s < NSRC; ++s)
                    if ((smk[k] >> s) & 1) nvy += DTF * buo_v[k] * sAmp[s * NT + t];
            }
            sV[0][vi] = nvy;
            sV[1][vi] = nvx;
        }
    };

    // ========== time loop: neighbor-flag sync only (no global barrier) ==========
    // flag[b] = #steps b has published. Skew between neighbors <= 1 step, so the
    // parity double-buffer separates readers/writers (proof: A starts step t+1 only
    // after B's flag >= t, and B flags t only after consuming A's ring(t-1)).
    for (int t = 0; t < NT; ++t) {
        const float* gsr = gstr + ((t + 1) & 1) * GSLOT;   // neighbors' state(t-1)
        float*       gsw = gstr + (t & 1) * GSLOT;         // my state(t)

        // interior velocity: no frame dependency -> overlaps neighbor drift
        do_vel(intm, t);

        // wait: my 8 neighbors must have published ring(t-1)
        if (t > 0 && myNbr >= 0) {
            while (__hip_atomic_load(&flags[myNbr], __ATOMIC_RELAXED,
                                     __HIP_MEMORY_SCOPE_AGENT) < t)
                __builtin_amdgcn_s_sleep(1);
        }
        __syncthreads();

        // P1: frame loads (6 sc1 loads, clustered) -> LDS frame
        float fr0[3], fr1[3];
        #pragma unroll
        for (int f = 0; f < 3; ++f) {
            fr0[f] = (t > 0 && fin[0]) ? cohload(&gsr[(f * NS + shot) * NCELL + fgi[0]]) : 0.0f;
            fr1[f] = (t > 0 && fin[1]) ? cohload(&gsr[(f * NS + shot) * NCELL + fgi[1]]) : 0.0f;
        }
        if (fval[0]) { sS[0][flidx[0]] = fr0[0]; sS[1][flidx[0]] = fr0[1]; sS[2][flidx[0]] = fr0[2]; }
        if (fval[1]) { sS[0][flidx[1]] = fr1[0]; sS[1][flidx[1]] = fr1[1]; sS[2][flidx[1]] = fr1[2]; }
        __syncthreads();

        // boundary velocity (needs frame)
        do_vel(bndm, t);
        __syncthreads();

        // receivers: vy after injection (LDS-resident)
        if (tid < rcnt)
            out[(shot * NREC + rl_r[tid]) * NT + t] = sV[0][rl_pos[tid]];

        // stress on tile; ring cells published immediately (same thread owns both)
        #pragma unroll
        for (int k = 0; k < KT; ++k) {
            if (!((ctm >> k) & 1)) continue;
            int si = sidx_t[k], vi = vidx_t[k];
            float by_ = byt[tyt[k] + 2], ay_ = ayt[tyt[k] + 2];
            float bx_ = bxt[txt[k] + 2], ax_ = axt[txt[k] + 2];
            float d, mm;
            d = (FC1 * (sV[0][vi + VS] - sV[0][vi]) + FC2 * (sV[0][vi + 2 * VS] - sV[0][vi - VS])) * INV_DX;
            mm = by_ * mvyy[k] + ay_ * d;  mvyy[k] = mm;  float dvy_y = d + mm;
            d = (FC1 * (sV[1][vi + 1] - sV[1][vi]) + FC2 * (sV[1][vi + 2] - sV[1][vi - 1])) * INV_DX;
            mm = bx_ * mvxx[k] + ax_ * d;  mvxx[k] = mm;  float dvx_x = d + mm;
            float nsyy = sS[0][si] + DTF * (l2m_t[k] * dvy_y + lam_t[k] * dvx_x);
            float nsxx = sS[2][si] + DTF * (lam_t[k] * dvy_y + l2m_t[k] * dvx_x);
            d = (FC1 * (sV[0][vi + 1] - sV[0][vi]) + FC2 * (sV[0][vi + 2] - sV[0][vi - 1])) * INV_DX;
            mm = bx_ * mvyx[k] + ax_ * d;  mvyx[k] = mm;  float dvy_x = d + mm;
            d = (FC1 * (sV[1][vi + VS] - sV[1][vi]) + FC2 * (sV[1][vi + 2 * VS] - sV[1][vi - VS])) * INV_DX;
            mm = by_ * mvxy[k] + ay_ * d;  mvxy[k] = mm;  float dvx_y = d + mm;
            float nsxy = sS[1][si] + DTF * mu_t[k] * (dvy_x + dvx_y);
            sS[0][si] = nsyy; sS[1][si] = nsxy; sS[2][si] = nsxx;
            if ((ringm >> k) & 1) {
                int gi = gidx_t[k];
                cohstore(&gsw[(0 * NS + shot) * NCELL + gi], nsyy);
                cohstore(&gsw[(1 * NS + shot) * NCELL + gi], nsxy);
                cohstore(&gsw[(2 * NS + shot) * NCELL + gi], nsxx);
            }
        }

        // publish: syncthreads drains all waves' ring stores (vmcnt(0)) -> flag store
        __syncthreads();
        if (tid == 0 && t < NT - 1)
            __hip_atomic_store(&flags[myBlk], t + 1, __ATOMIC_RELAXED,
                               __HIP_MEMORY_SCOPE_AGENT);
    }
}

extern "C" void kernel_launch(void* const* d_in, const int* in_sizes, int n_in,
                              void* d_out, int out_size, void* d_ws, size_t ws_size,
                              hipStream_t stream) {
    const float* lamb    = (const float*)d_in[0];
    const float* mu      = (const float*)d_in[1];
    const float* buoy    = (const float*)d_in[2];
    const float* amps    = (const float*)d_in[3];
    const int*   src_loc = (const int*)d_in[4];
    const int*   rec_loc = (const int*)d_in[5];
    float* ws  = (float*)d_ws;
    float* out = (float*)d_out;

    // zero per-block publish flags (ws is poisoned 0xAA before every call)
    hipMemsetAsync(ws + FLG_OFF, 0, NBLK * sizeof(int), stream);

    elastic_fused<<<NBLK, NTHR, 0, stream>>>(lamb, mu, buoy, amps, src_loc, rec_loc, out, ws);
}